// Round 10
// baseline (40.834 us; speedup 1.0000x reference)
//
#include <hip/hip_runtime.h>
#include <math.h>

// LogicConv2d, prep + 2-tile software-pipelined main (T14 async-stage).
//
// prep (1 block): softmax(sel_a), softmax(sel_b), collapse 16-way mix to
//   out = Cab*ab + Ca*a + Cb*b + C0. tab[81][24] floats in d_ws, readable as
//   6 aligned float4 per unit: q0=sa[0:4] q1=sa[4:8] q2={sa8,sb0,sb1,sb2}
//   q3=sb[3:7] q4={sb7,sb8,Cab,Ca} q5={Cb,C0,-,-}.
//
// main: 1024 blocks x 256 threads; block handles tiles {bid, bid+1024} of
//   64 batches each through ONE 20.7 KB LDS buffer.
//   Pipeline: tile1 loads are issued into regs BEFORE tile0 compute and
//   ds_written AFTER tile0 writeback (same per-thread slot -> no extra
//   barrier; in-order VMEM retirement means the 162 weight loads issued
//   after them guarantee the prefetch regs have landed -> stall-free).
//   Chip-wide effect: read stream overlaps compute + write stream instead
//   of the previous lockstep read-burst / bubble / write-burst.
//   Compute: wave w<3 owns units 27w..27w+26 == patch-row w (its private
//   row-slice of the tile, read & written in place); weights via
//   wave-uniform float4 loads (L2-hot broadcast); fully unrolled.

#define NB      131072
#define NUNITS  81
#define BPB     64             // batches per tile
#define THREADS 256
#define NBLK    1024           // blocks; each does tiles bid, bid+NBLK
#define REC     24             // floats per unit record (96 B)
#define CHUNKS  (BPB * 81 / 4) // 1296 float4 per tile

__global__ __launch_bounds__(256)
void logic_prep_kernel(const float* __restrict__ sa_logits,
                       const float* __restrict__ sb_logits,
                       const float* __restrict__ op_logits,
                       float* __restrict__ tab)
{
    const int tid = threadIdx.x;
    if (tid < 81) {
        const int u = tid;
        float v[9], m = -1e30f;
        #pragma unroll
        for (int i = 0; i < 9; ++i) { v[i] = sa_logits[u * 9 + i]; m = fmaxf(m, v[i]); }
        float s = 0.f;
        #pragma unroll
        for (int i = 0; i < 9; ++i) { v[i] = expf(v[i] - m); s += v[i]; }
        const float r = 1.f / s;
        #pragma unroll
        for (int i = 0; i < 9; ++i) tab[u * REC + i] = v[i] * r;
    } else if (tid < 162) {
        const int u = tid - 81;
        float v[9], m = -1e30f;
        #pragma unroll
        for (int i = 0; i < 9; ++i) { v[i] = sb_logits[u * 9 + i]; m = fmaxf(m, v[i]); }
        float s = 0.f;
        #pragma unroll
        for (int i = 0; i < 9; ++i) { v[i] = expf(v[i] - m); s += v[i]; }
        const float r = 1.f / s;
        #pragma unroll
        for (int i = 0; i < 9; ++i) tab[u * REC + 9 + i] = v[i] * r;
    } else if (tid < 243) {
        const int u = tid - 162;
        float v[16], m = -1e30f;
        #pragma unroll
        for (int i = 0; i < 16; ++i) { v[i] = op_logits[u * 16 + i]; m = fmaxf(m, v[i]); }
        float s = 0.f;
        #pragma unroll
        for (int i = 0; i < 16; ++i) { v[i] = expf(v[i] - m); s += v[i]; }
        const float r = 1.f / s;
        #pragma unroll
        for (int i = 0; i < 16; ++i) v[i] *= r;
        const float cab = v[1] - v[2] - v[4] - 2.f*v[6] - v[7] + v[8] + 2.f*v[9]
                        + v[11] + v[13] - v[14];
        const float ca  = v[2] + v[3] + v[6] + v[7] - v[8] - v[9] - v[12] - v[13];
        const float cb  = v[4] + v[5] + v[6] + v[7] - v[8] - v[9] - v[10] - v[11];
        const float c0  = v[8] + v[9] + v[10] + v[11] + v[12] + v[13] + v[14] + v[15];
        tab[u * REC + 18] = cab;
        tab[u * REC + 19] = ca;
        tab[u * REC + 20] = cb;
        tab[u * REC + 21] = c0;
    }
}

__device__ __forceinline__
void compute_tile(float* __restrict__ s_tile, const float* __restrict__ tab,
                  int lane, int wavei)
{
    if (wavei < 3) {
        float* my = s_tile + lane * 81 + wavei * 27;    // private slice: r==w

        float in[27];                                    // img rows 3w..3w+2
        #pragma unroll
        for (int j = 0; j < 27; ++j) in[j] = my[j];

        const float4* __restrict__ wt4 =
            (const float4*)(tab + (size_t)wavei * 27 * REC);  // uniform base

        #pragma unroll
        for (int j = 0; j < 27; ++j) {                   // unit u = 27*wavei+j
            const int q = j / 9;                         // patch col within row
            const float4 q0 = wt4[j * 6 + 0];
            const float4 q1 = wt4[j * 6 + 1];
            const float4 q2 = wt4[j * 6 + 2];
            const float4 q3 = wt4[j * 6 + 3];
            const float4 q4 = wt4[j * 6 + 4];
            const float4 q5 = wt4[j * 6 + 5];
            const float wa[9] = { q0.x, q0.y, q0.z, q0.w, q1.x, q1.y, q1.z, q1.w, q2.x };
            const float wb[9] = { q2.y, q2.z, q2.w, q3.x, q3.y, q3.z, q3.w, q4.x, q4.y };
            float a = 0.f, b = 0.f;
            #pragma unroll
            for (int i = 0; i < 9; ++i) {
                const float xi = in[q * 3 + (i / 3) * 9 + (i % 3)];
                a = fmaf(xi, wa[i], a);
                b = fmaf(xi, wb[i], b);
            }
            // q4.z=Cab q4.w=Ca q5.x=Cb q5.y=C0
            my[j] = fmaf(q4.z, a * b, fmaf(q4.w, a, fmaf(q5.x, b, q5.y)));
        }
    }
}

__global__ __launch_bounds__(THREADS, 4)
void logic_main_kernel(const float* __restrict__ x,
                       const float* __restrict__ tab,
                       float* __restrict__ out)
{
    __shared__ float s_tile[BPB * 81];     // single buffer, 20736 B

    const int tid   = threadIdx.x;
    const int lane  = tid & 63;
    const int wavei = __builtin_amdgcn_readfirstlane(tid >> 6);
    const int bid   = blockIdx.x;

    const float4* __restrict__ x4 = (const float4*)x;
    float4* __restrict__ o4       = (float4*)out;
    float4* s4 = (float4*)s_tile;

    float4 r[6];

    // ---- prologue: tile0 -> regs -> LDS ----
    {
        const float4* g = x4 + (size_t)bid * CHUNKS;
        #pragma unroll
        for (int k = 0; k < 6; ++k) {
            int j = tid + k * THREADS;
            if (j < CHUNKS) r[k] = g[j];
        }
    }
    #pragma unroll
    for (int k = 0; k < 6; ++k) {
        int j = tid + k * THREADS;
        if (j < CHUNKS) s4[j] = r[k];
    }
    __syncthreads();

    // ================= tile 0 =================
    // prefetch tile 1 into regs (in flight across compute; in-order VMEM
    // retirement + the weight loads below guarantee arrival by ds_write time)
    {
        const float4* g = x4 + (size_t)(bid + NBLK) * CHUNKS;
        #pragma unroll
        for (int k = 0; k < 6; ++k) {
            int j = tid + k * THREADS;
            if (j < CHUNKS) r[k] = g[j];
        }
    }
    __builtin_amdgcn_sched_barrier(0);   // pin prefetch issue before compute

    compute_tile(s_tile, tab, lane, wavei);
    __syncthreads();

    // writeback tile0 + stage tile1 into the SAME per-thread slots
    {
        float4* g = o4 + (size_t)bid * CHUNKS;
        #pragma unroll
        for (int k = 0; k < 6; ++k) {
            int j = tid + k * THREADS;
            if (j < CHUNKS) {
                float4 v = s4[j];        // ds_read (old tile0 result)
                g[j] = v;                // global_store (lingers)
                s4[j] = r[k];            // ds_write tile1 (same thread+slot)
            }
        }
    }
    __syncthreads();

    // ================= tile 1 =================
    compute_tile(s_tile, tab, lane, wavei);
    __syncthreads();

    {
        float4* g = o4 + (size_t)(bid + NBLK) * CHUNKS;
        #pragma unroll
        for (int k = 0; k < 6; ++k) {
            int j = tid + k * THREADS;
            if (j < CHUNKS) g[j] = s4[j];
        }
    }
}

extern "C" void kernel_launch(void* const* d_in, const int* in_sizes, int n_in,
                              void* d_out, int out_size, void* d_ws, size_t ws_size,
                              hipStream_t stream)
{
    const float* x  = (const float*)d_in[0];
    const float* sa = (const float*)d_in[1];
    const float* sb = (const float*)d_in[2];
    const float* op = (const float*)d_in[3];
    float* tab  = (float*)d_ws;             // 81*24*4 = 7776 B
    float* outp = (float*)d_out;

    logic_prep_kernel<<<1, 256, 0, stream>>>(sa, sb, op, tab);
    logic_main_kernel<<<NBLK, THREADS, 0, stream>>>(x, tab, outp);
}

// Round 11
// 32.928 us; speedup vs baseline: 1.2401x; 1.2401x over previous
//
#include <hip/hip_runtime.h>
#include <math.h>

// LogicConv2d, prep + small-tile max-concurrency main.
//
// prep (1 block): softmax(sel_a), softmax(sel_b), collapse 16-way mix to
//   out = Cab*ab + Ca*a + Cb*b + C0. tab[81][24] floats in d_ws, readable as
//   6 aligned float4 per unit: q0=sa[0:4] q1=sa[4:8] q2={sa8,sb0,sb1,sb2}
//   q3=sb[3:7] q4={sb7,sb8,Cab,Ca} q5={Cb,C0,-,-}.
//
// main: 4096 blocks x 256 threads <-> 32 batches each. LDS = 10.4 KB ->
//   8 blocks/CU (32 waves = HW cap) and 8 INDEPENDENT barrier groups per CU
//   (R1-R10 evidence: all pipes <25% busy at a 30 us plateau; the only
//   untested lever is latency-hiding granularity — waves of one block stall
//   together at vmcnt(0)+barrier, so independent-block count and per-phase
//   critical path are what hide memory latency). Staging via global_load_lds
//   DMA; compute: wave w<3, lanes 0-31 <-> batches, units 27w..27w+26
//   (= patch-row w); weights via wave-uniform float4 loads (L2-hot);
//   fully unrolled; results overwrite the tile in place.

#define NB      131072
#define NUNITS  81
#define BPB     32             // batches per block
#define THREADS 256
#define NBLK    (NB / BPB)     // 4096
#define REC     24             // floats per unit record (96 B)
#define CHUNKS  (BPB * 81 / 4) // 648 float4 per tile

typedef __attribute__((address_space(1))) const void GAS;
typedef __attribute__((address_space(3))) void LAS;

__global__ __launch_bounds__(256)
void logic_prep_kernel(const float* __restrict__ sa_logits,
                       const float* __restrict__ sb_logits,
                       const float* __restrict__ op_logits,
                       float* __restrict__ tab)
{
    const int tid = threadIdx.x;
    if (tid < 81) {
        const int u = tid;
        float v[9], m = -1e30f;
        #pragma unroll
        for (int i = 0; i < 9; ++i) { v[i] = sa_logits[u * 9 + i]; m = fmaxf(m, v[i]); }
        float s = 0.f;
        #pragma unroll
        for (int i = 0; i < 9; ++i) { v[i] = expf(v[i] - m); s += v[i]; }
        const float r = 1.f / s;
        #pragma unroll
        for (int i = 0; i < 9; ++i) tab[u * REC + i] = v[i] * r;
    } else if (tid < 162) {
        const int u = tid - 81;
        float v[9], m = -1e30f;
        #pragma unroll
        for (int i = 0; i < 9; ++i) { v[i] = sb_logits[u * 9 + i]; m = fmaxf(m, v[i]); }
        float s = 0.f;
        #pragma unroll
        for (int i = 0; i < 9; ++i) { v[i] = expf(v[i] - m); s += v[i]; }
        const float r = 1.f / s;
        #pragma unroll
        for (int i = 0; i < 9; ++i) tab[u * REC + 9 + i] = v[i] * r;
    } else if (tid < 243) {
        const int u = tid - 162;
        float v[16], m = -1e30f;
        #pragma unroll
        for (int i = 0; i < 16; ++i) { v[i] = op_logits[u * 16 + i]; m = fmaxf(m, v[i]); }
        float s = 0.f;
        #pragma unroll
        for (int i = 0; i < 16; ++i) { v[i] = expf(v[i] - m); s += v[i]; }
        const float r = 1.f / s;
        #pragma unroll
        for (int i = 0; i < 16; ++i) v[i] *= r;
        const float cab = v[1] - v[2] - v[4] - 2.f*v[6] - v[7] + v[8] + 2.f*v[9]
                        + v[11] + v[13] - v[14];
        const float ca  = v[2] + v[3] + v[6] + v[7] - v[8] - v[9] - v[12] - v[13];
        const float cb  = v[4] + v[5] + v[6] + v[7] - v[8] - v[9] - v[10] - v[11];
        const float c0  = v[8] + v[9] + v[10] + v[11] + v[12] + v[13] + v[14] + v[15];
        tab[u * REC + 18] = cab;
        tab[u * REC + 19] = ca;
        tab[u * REC + 20] = cb;
        tab[u * REC + 21] = c0;
    }
}

__global__ __launch_bounds__(THREADS, 8)
void logic_main_kernel(const float* __restrict__ x,
                       const float* __restrict__ tab,
                       float* __restrict__ out)
{
    __shared__ float s_tile[BPB * 81];     // 10368 B — the only LDS

    const int tid   = threadIdx.x;
    const int lane  = tid & 63;
    const int wavei = __builtin_amdgcn_readfirstlane(tid >> 6);
    const size_t b0 = (size_t)blockIdx.x * BPB;

    // ---- stage input tile via global->LDS DMA (648 f4 / 256 threads) ----
    {
        const float4* gsrc = (const float4*)(x + b0 * 81);
        #pragma unroll
        for (int k = 0; k < 3; ++k) {
            const int j = tid + k * THREADS;
            if (j < CHUNKS) {
                // wave-uniform LDS base; hardware adds lane*16
                float* lbase = s_tile + (size_t)(k * THREADS + wavei * 64) * 4;
                __builtin_amdgcn_global_load_lds((GAS*)(gsrc + j), (LAS*)lbase,
                                                 16, 0, 0);
            }
        }
    }
    __syncthreads();

    // ---- compute: wave w<3, lanes 0-31 <-> batches, units 27w..27w+26 ----
    if (wavei < 3 && lane < BPB) {
        float* my = s_tile + lane * 81 + wavei * 27;   // read == write slice
                                                       // stride 81 over 32 lanes:
                                                       // 81 mod 32 = 17 -> conflict-free
        float in[27];                                   // img rows 3w..3w+2
        #pragma unroll
        for (int j = 0; j < 27; ++j) in[j] = my[j];

        const float4* __restrict__ wt4 =
            (const float4*)(tab + (size_t)wavei * 27 * REC);  // uniform base

        #pragma unroll
        for (int j = 0; j < 27; ++j) {                  // unit u = 27*wavei+j
            const int q = j / 9;                        // patch col within row
            const float4 q0 = wt4[j * 6 + 0];
            const float4 q1 = wt4[j * 6 + 1];
            const float4 q2 = wt4[j * 6 + 2];
            const float4 q3 = wt4[j * 6 + 3];
            const float4 q4 = wt4[j * 6 + 4];
            const float4 q5 = wt4[j * 6 + 5];
            const float wa[9] = { q0.x, q0.y, q0.z, q0.w, q1.x, q1.y, q1.z, q1.w, q2.x };
            const float wb[9] = { q2.y, q2.z, q2.w, q3.x, q3.y, q3.z, q3.w, q4.x, q4.y };
            float a = 0.f, b = 0.f;
            #pragma unroll
            for (int i = 0; i < 9; ++i) {
                const float xi = in[q * 3 + (i / 3) * 9 + (i % 3)];
                a = fmaf(xi, wa[i], a);
                b = fmaf(xi, wb[i], b);
            }
            // q4.z=Cab q4.w=Ca q5.x=Cb q5.y=C0
            my[j] = fmaf(q4.z, a * b, fmaf(q4.w, a, fmaf(q5.x, b, q5.y)));
        }
    }

    __syncthreads();

    // ---- coalesced writeback, all 4 waves ----
    {
        const float4* s4 = (const float4*)s_tile;
        float4* gdst = (float4*)(out + b0 * 81);
        #pragma unroll
        for (int k = 0; k < 3; ++k) {
            const int j = tid + k * THREADS;
            if (j < CHUNKS) gdst[j] = s4[j];
        }
    }
}

extern "C" void kernel_launch(void* const* d_in, const int* in_sizes, int n_in,
                              void* d_out, int out_size, void* d_ws, size_t ws_size,
                              hipStream_t stream)
{
    const float* x  = (const float*)d_in[0];
    const float* sa = (const float*)d_in[1];
    const float* sb = (const float*)d_in[2];
    const float* op = (const float*)d_in[3];
    float* tab  = (float*)d_ws;             // 81*24*4 = 7776 B
    float* outp = (float*)d_out;

    logic_prep_kernel<<<1, 256, 0, stream>>>(sa, sb, op, tab);
    logic_main_kernel<<<NBLK, THREADS, 0, stream>>>(x, tab, outp);
}